// Round 5
// baseline (111.868 us; speedup 1.0000x reference)
//
#include <hip/hip_runtime.h>
#include <math.h>

// Problem constants
#define BB 16      // batch
#define LL 32      // L
#define AA 2046    // attributor cols
#define MM 2048    // M = A + 2
#define NROWS 192  // 6L
#define CT 64      // column tiles
#define CPB 32     // columns per block (c-space)

// c-space mapping: c in [0,2045] -> n = c+1 (att col c); c=2046 -> n=0 (user
// column, no W1); c=2047 -> n=M-1 (item column, no W1). Keeps att float2
// loads 8B-aligned; value phase shares the layout with s/t.
//
// NOTE: resubmission of round-4 source — previous bench died in container
// acquire ("failed twice"), not in the kernel; code audited for OOB/hangs.

// ---------------------------------------------------------------------------
// Single fused kernel (plus 4KB memset). grid (64 ctiles, 16 b) x 256 thr
// = 1024 blocks (4 blocks/CU, 16 waves/CU).
// Per block (owns 32 c-space columns end-to-end, all cross-thread state LDS):
//   prep   : redundant K/Q projections -> u_j[64], v_j[64] weights
//   load   : thread (cq=tid&7, rg=tid>>3) loads ALL its att/W1 data in one
//            burst: 4 st-rows (rg<16: Q rows, else K rows) + 2 value rows
//            (128+rg*2+i), relu-products held in registers
//   st     : partial s/t dots -> stS (LDS)
//   cweight: 64 threads combine -> cs[j][32] = sigmoid(d_j)*adj (LDS only)
//   value  : g[i][j] = sum_k vva[i][k]*cs[j][...]; shuffle-reduce over the
//            8 col-quads; gred (LDS)
//   project: 64 threads: out[b,l,j] += sum_rv W2[128+rv,l]*gred[rv], atomic
// ---------------------------------------------------------------------------
__global__ __launch_bounds__(256) void fused_kernel(
    const float* __restrict__ user, const float* __restrict__ item,
    const float* __restrict__ att, const float* __restrict__ adj,
    const float* __restrict__ iw, const float* __restrict__ W1,
    const float* __restrict__ W2, float* __restrict__ out) {
  const int ctile = blockIdx.x, b = blockIdx.y, tid = threadIdx.x;
  __shared__ float KQ[4][LL];
  __shared__ float uvs[4][64];
  __shared__ float stS[32][8][4][2];  // [rowgroup][colquad][colInQuad][j]
  __shared__ float cs[2][CPB];
  __shared__ float gred[32][2][2];    // [rowgroup][rowInGroup][j]

  // ---- prep stage 1: K/Q boundary projections ----
  if (tid < 128) {
    const int q = tid >> 5, l = tid & 31;
    const float* __restrict__ src = (q == 0 || q == 2) ? user : item;
    const int rbase = (q < 2) ? 64 : 0;  // K rows 64..127, Q rows 0..63
    float acc = 0.f;
#pragma unroll
    for (int r = 0; r < 64; ++r)
      acc += fmaxf(src[b * NROWS + rbase + r], 0.f) * W2[(rbase + r) * LL + l];
    KQ[q][l] = acc;  // 0:K0(user) 1:K1(item) 2:Q0(user) 3:Q1(item)
  }
  __syncthreads();
  {  // ---- prep stage 2: u/v weights ----
    const int which = tid >> 6, r = tid & 63;
    const int wrow = (which < 2) ? r : 64 + r;
    float acc = 0.f;
#pragma unroll
    for (int l = 0; l < LL; ++l) acc += W2[wrow * LL + l] * KQ[which][l];
    uvs[which][r] = acc;  // 0:u0 1:u1 2:v0 3:v1
  }
  __syncthreads();

  const int cq = tid & 7, rg = tid >> 3;
  const int c0 = ctile * CPB + cq * 4;
  const bool tail = (c0 + 2 >= AA);  // only ctile==63, cq==7

  // ---- single global-load burst: 4 st-rows + 2 value-rows, 4 cols each ----
  float vst[4][4];  // relu(att*W1) for st rows  [rowInGroup][col]
  float vva[2][4];  // relu(att*W1) for value rows
  const int sbase = (rg < 16) ? 0 : 64;  // Q rows vs K rows
  const int r0 = sbase + (rg & 15) * 4;
#pragma unroll
  for (int i = 0; i < 4; ++i) {
    const int r = r0 + i;
    const size_t arow = (size_t)(b * NROWS + r) * AA;
    const size_t wrow = (size_t)r * AA;
    const float2 av0 = *(const float2*)(att + arow + c0);
    const float2 wv0 = *(const float2*)(W1 + wrow + c0);
    vst[i][0] = fmaxf(av0.x * wv0.x, 0.f);
    vst[i][1] = fmaxf(av0.y * wv0.y, 0.f);
    if (!tail) {
      const float2 av1 = *(const float2*)(att + arow + c0 + 2);
      const float2 wv1 = *(const float2*)(W1 + wrow + c0 + 2);
      vst[i][2] = fmaxf(av1.x * wv1.x, 0.f);
      vst[i][3] = fmaxf(av1.y * wv1.y, 0.f);
    } else {  // c 2046 -> user (n=0), 2047 -> item (n=M-1)
      vst[i][2] = fmaxf(user[b * NROWS + r], 0.f);
      vst[i][3] = fmaxf(item[b * NROWS + r], 0.f);
    }
  }
#pragma unroll
  for (int i = 0; i < 2; ++i) {
    const int r = 128 + rg * 2 + i;
    const size_t arow = (size_t)(b * NROWS + r) * AA;
    const size_t wrow = (size_t)r * AA;
    const float2 av0 = *(const float2*)(att + arow + c0);
    const float2 wv0 = *(const float2*)(W1 + wrow + c0);
    vva[i][0] = fmaxf(av0.x * wv0.x, 0.f);
    vva[i][1] = fmaxf(av0.y * wv0.y, 0.f);
    if (!tail) {
      const float2 av1 = *(const float2*)(att + arow + c0 + 2);
      const float2 wv1 = *(const float2*)(W1 + wrow + c0 + 2);
      vva[i][2] = fmaxf(av1.x * wv1.x, 0.f);
      vva[i][3] = fmaxf(av1.y * wv1.y, 0.f);
    } else {
      vva[i][2] = fmaxf(user[b * NROWS + r], 0.f);
      vva[i][3] = fmaxf(item[b * NROWS + r], 0.f);
    }
  }

  // ---- st partials (registers -> LDS) ----
  {
    const float* __restrict__ wj0 = uvs[(rg < 16) ? 0 : 2];
    const float* __restrict__ wj1 = uvs[(rg < 16) ? 1 : 3];
    float a[4][2] = {};
#pragma unroll
    for (int i = 0; i < 4; ++i) {
      const int widx = (rg & 15) * 4 + i;  // == r - sbase
      const float u0 = wj0[widx], u1 = wj1[widx];
#pragma unroll
      for (int k = 0; k < 4; ++k) {
        a[k][0] += vst[i][k] * u0;
        a[k][1] += vst[i][k] * u1;
      }
    }
#pragma unroll
    for (int k = 0; k < 4; ++k) {
      stS[rg][cq][k][0] = a[k][0];
      stS[rg][cq][k][1] = a[k][1];
    }
  }
  __syncthreads();

  // ---- cweight: 32 cols x 2 targets ----
  if (tid < 64) {
    const int col = tid >> 1, j = tid & 1;
    const int q = col >> 2, ci = col & 3;
    float s = 0.f, t = 0.f;
#pragma unroll
    for (int g = 0; g < 16; ++g) s += stS[g][q][ci][j];
#pragma unroll
    for (int g = 16; g < 32; ++g) t += stS[g][q][ci][j];
    const int cc = ctile * CPB + col;
    const int n = (cc < AA) ? cc + 1 : ((cc == AA) ? 0 : MM - 1);
    const size_t tcol = j ? (MM - 1) : 0;
    const float an = adj[(size_t)n * MM + tcol];
    const float wn = an * iw[(size_t)n * MM + tcol];
    const float wt = adj[tcol * MM + n] * iw[tcol * MM + n];
    const float d = s * wn - t * wt;
    const float e = expf(-fabsf(d));
    const float sig = (d > 0.f) ? 1.f / (1.f + e) : e / (1.f + e);
    cs[j][col] = sig * an;
  }
  __syncthreads();

  // ---- value: multiply held relu-products by cs, reduce over col-quads ----
  {
    float g[2][2];
#pragma unroll
    for (int i = 0; i < 2; ++i) {
      g[i][0] = vva[i][0] * cs[0][cq * 4] + vva[i][1] * cs[0][cq * 4 + 1] +
                vva[i][2] * cs[0][cq * 4 + 2] + vva[i][3] * cs[0][cq * 4 + 3];
      g[i][1] = vva[i][0] * cs[1][cq * 4] + vva[i][1] * cs[1][cq * 4 + 1] +
                vva[i][2] * cs[1][cq * 4 + 2] + vva[i][3] * cs[1][cq * 4 + 3];
    }
#pragma unroll
    for (int m = 4; m >= 1; m >>= 1) {
#pragma unroll
      for (int i = 0; i < 2; ++i) {
        g[i][0] += __shfl_xor(g[i][0], m, 8);
        g[i][1] += __shfl_xor(g[i][1], m, 8);
      }
    }
    if (cq == 0) {
#pragma unroll
      for (int i = 0; i < 2; ++i) {
        gred[rg][i][0] = g[i][0];
        gred[rg][i][1] = g[i][1];
      }
    }
  }
  __syncthreads();

  // ---- project partial g through W2, atomic-accumulate ----
  if (tid < 64) {
    const int l = tid & 31, j = tid >> 5;
    float acc = 0.f;
#pragma unroll
    for (int rv = 0; rv < 64; ++rv)
      acc += W2[(128 + rv) * LL + l] * gred[rv >> 1][rv & 1][j];
    atomicAdd(&out[b * (LL * 2) + l * 2 + j], acc);
  }
}

extern "C" void kernel_launch(void* const* d_in, const int* in_sizes, int n_in,
                              void* d_out, int out_size, void* d_ws,
                              size_t ws_size, hipStream_t stream) {
  const float* user = (const float*)d_in[0];
  const float* item = (const float*)d_in[1];
  const float* att = (const float*)d_in[2];
  const float* adj = (const float*)d_in[3];
  const float* iw = (const float*)d_in[4];
  const float* W1 = (const float*)d_in[5];
  const float* W2 = (const float*)d_in[6];
  float* out = (float*)d_out;

  hipMemsetAsync(d_out, 0, sizeof(float) * (size_t)out_size, stream);
  fused_kernel<<<dim3(CT, BB), 256, 0, stream>>>(user, item, att, adj, iw, W1,
                                                 W2, out);
}

// Round 6
// 110.310 us; speedup vs baseline: 1.0141x; 1.0141x over previous
//
#include <hip/hip_runtime.h>
#include <math.h>

// Problem constants
#define BB 16      // batch
#define LL 32      // L
#define AA 2046    // attributor cols
#define MM 2048    // M = A + 2
#define NROWS 192  // 6L
#define CT 32      // column tiles
#define CPB 64     // columns per block (c-space)

// c-space mapping: c in [0,2045] -> n = c+1 (att col c); c=2046 -> n=0 (user
// column, no W1); c=2047 -> n=M-1 (item column, no W1).
//
// Round-6 = round-3 champion geometry (best measured) + latency-hoisting:
//   * value-row att/W1 raw loads issued at kernel top (consumed post-cweight)
//   * adj/iw scattered scalars for cweight prefetched at kernel top
//   * value relu-products computed before barrier 1
// Phase graph unchanged; algebra identical to the verified round-3 kernel.

__global__ __launch_bounds__(256) void fused_kernel(
    const float* __restrict__ user, const float* __restrict__ item,
    const float* __restrict__ att, const float* __restrict__ adj,
    const float* __restrict__ iw, const float* __restrict__ W1,
    const float* __restrict__ W2, float* __restrict__ out) {
  const int ctile = blockIdx.x, b = blockIdx.y, tid = threadIdx.x;
  __shared__ float KQ[4][LL];
  __shared__ float uvs[4][64];
  __shared__ float stS[16][16][4][2];  // [rowgroup][colquad][colInQuad][j]
  __shared__ float cs[2][CPB];
  __shared__ float gred[16][4][2];     // [rowgroup][rowInGroup][j]

  const int cq = tid & 15, rg = tid >> 4;
  const int c0 = ctile * CPB + cq * 4;
  const bool tail = (c0 + 2 >= AA);  // only ctile==31, cq==15

  // ---- EARLY ISSUE 1: value-row raw loads (rows 128+rg*4+i, 4 cols) ----
  float2 ava0[4], wva0[4], ava1[4], wva1[4];
  float vtu[4], vti[4];
#pragma unroll
  for (int i = 0; i < 4; ++i) {
    const int r = 128 + rg * 4 + i;
    const size_t arow = (size_t)(b * NROWS + r) * AA;
    const size_t wrow = (size_t)r * AA;
    ava0[i] = *(const float2*)(att + arow + c0);
    wva0[i] = *(const float2*)(W1 + wrow + c0);
    if (!tail) {
      ava1[i] = *(const float2*)(att + arow + c0 + 2);
      wva1[i] = *(const float2*)(W1 + wrow + c0 + 2);
    } else {  // c 2046 -> user (n=0), 2047 -> item (n=M-1)
      vtu[i] = user[b * NROWS + r];
      vti[i] = item[b * NROWS + r];
    }
  }

  // ---- EARLY ISSUE 2: adj/iw prefetch for cweight (tid<128) ----
  float anP = 0.f, wnP = 0.f, atP = 0.f, wtP = 0.f;
  if (tid < 128) {
    const int col = tid >> 1, j = tid & 1;
    const int cc = ctile * CPB + col;
    const int n = (cc < AA) ? cc + 1 : ((cc == AA) ? 0 : MM - 1);
    const size_t tcol = j ? (MM - 1) : 0;
    anP = adj[(size_t)n * MM + tcol];
    wnP = iw[(size_t)n * MM + tcol];
    atP = adj[tcol * MM + n];
    wtP = iw[tcol * MM + n];
  }

  // ---- prep stage 1: K/Q boundary projections ----
  if (tid < 128) {
    const int q = tid >> 5, l = tid & 31;
    const float* __restrict__ src = (q == 0 || q == 2) ? user : item;
    const int rbase = (q < 2) ? 64 : 0;  // K rows 64..127, Q rows 0..63
    float acc = 0.f;
#pragma unroll
    for (int r = 0; r < 64; ++r)
      acc += fmaxf(src[b * NROWS + rbase + r], 0.f) * W2[(rbase + r) * LL + l];
    KQ[q][l] = acc;  // 0:K0(user) 1:K1(item) 2:Q0(user) 3:Q1(item)
  }
  __syncthreads();
  {  // ---- prep stage 2: u/v weights ----
    const int which = tid >> 6, r = tid & 63;
    const int wrow = (which < 2) ? r : 64 + r;
    float acc = 0.f;
#pragma unroll
    for (int l = 0; l < LL; ++l) acc += W2[wrow * LL + l] * KQ[which][l];
    uvs[which][r] = acc;  // 0:u0 1:u1 2:v0 3:v1
  }
  __syncthreads();

  // ---- s/t partials: col-quad x 8-row group (in-loop consumption) ----
  {
    const float* __restrict__ wj0 = uvs[(rg < 8) ? 0 : 2];
    const float* __restrict__ wj1 = uvs[(rg < 8) ? 1 : 3];
    const int rbase = (rg < 8) ? 0 : 64;
    const int rrow0 = (rg & 7) * 8 + rbase;
    float a[4][2] = {};
#pragma unroll
    for (int i = 0; i < 8; ++i) {
      const int r = rrow0 + i;
      const int widx = r - rbase;
      const size_t arow = (size_t)(b * NROWS + r) * AA;
      const size_t wrow = (size_t)r * AA;
      const float2 av0 = *(const float2*)(att + arow + c0);
      const float2 wv0 = *(const float2*)(W1 + wrow + c0);
      const float v0 = fmaxf(av0.x * wv0.x, 0.f);
      const float v1 = fmaxf(av0.y * wv0.y, 0.f);
      float v2, v3;
      if (!tail) {
        const float2 av1 = *(const float2*)(att + arow + c0 + 2);
        const float2 wv1 = *(const float2*)(W1 + wrow + c0 + 2);
        v2 = fmaxf(av1.x * wv1.x, 0.f);
        v3 = fmaxf(av1.y * wv1.y, 0.f);
      } else {  // c 2046 -> user, 2047 -> item (no W1)
        v2 = fmaxf(user[b * NROWS + r], 0.f);
        v3 = fmaxf(item[b * NROWS + r], 0.f);
      }
      const float u0 = wj0[widx], u1 = wj1[widx];
      a[0][0] += v0 * u0; a[0][1] += v0 * u1;
      a[1][0] += v1 * u0; a[1][1] += v1 * u1;
      a[2][0] += v2 * u0; a[2][1] += v2 * u1;
      a[3][0] += v3 * u0; a[3][1] += v3 * u1;
    }
#pragma unroll
    for (int k = 0; k < 4; ++k) {
      stS[rg][cq][k][0] = a[k][0];
      stS[rg][cq][k][1] = a[k][1];
    }
  }

  // ---- value relu-products from the hoisted raw loads (pre-barrier) ----
  float vva[4][4];
#pragma unroll
  for (int i = 0; i < 4; ++i) {
    vva[i][0] = fmaxf(ava0[i].x * wva0[i].x, 0.f);
    vva[i][1] = fmaxf(ava0[i].y * wva0[i].y, 0.f);
    if (!tail) {
      vva[i][2] = fmaxf(ava1[i].x * wva1[i].x, 0.f);
      vva[i][3] = fmaxf(ava1[i].y * wva1[i].y, 0.f);
    } else {
      vva[i][2] = fmaxf(vtu[i], 0.f);
      vva[i][3] = fmaxf(vti[i], 0.f);
    }
  }
  __syncthreads();

  // ---- cweight: 64 cols x 2 targets (prefetched adj/iw) ----
  if (tid < 128) {
    const int col = tid >> 1, j = tid & 1;
    const int q = col >> 2, ci = col & 3;
    float s = 0.f, t = 0.f;
#pragma unroll
    for (int g = 0; g < 8; ++g) s += stS[g][q][ci][j];
#pragma unroll
    for (int g = 8; g < 16; ++g) t += stS[g][q][ci][j];
    const float wn = anP * wnP;
    const float wt = atP * wtP;
    const float d = s * wn - t * wt;
    const float e = expf(-fabsf(d));
    const float sig = (d > 0.f) ? 1.f / (1.f + e) : e / (1.f + e);
    cs[j][col] = sig * anP;
  }
  __syncthreads();

  // ---- value: held products x cs, reduce over the 16 col-quads ----
  {
    const float c00 = cs[0][cq * 4], c01 = cs[0][cq * 4 + 1];
    const float c02 = cs[0][cq * 4 + 2], c03 = cs[0][cq * 4 + 3];
    const float c10 = cs[1][cq * 4], c11 = cs[1][cq * 4 + 1];
    const float c12 = cs[1][cq * 4 + 2], c13 = cs[1][cq * 4 + 3];
    float g[4][2];
#pragma unroll
    for (int i = 0; i < 4; ++i) {
      g[i][0] = vva[i][0] * c00 + vva[i][1] * c01 + vva[i][2] * c02 +
                vva[i][3] * c03;
      g[i][1] = vva[i][0] * c10 + vva[i][1] * c11 + vva[i][2] * c12 +
                vva[i][3] * c13;
    }
#pragma unroll
    for (int m = 8; m >= 1; m >>= 1) {
#pragma unroll
      for (int i = 0; i < 4; ++i) {
        g[i][0] += __shfl_xor(g[i][0], m, 16);
        g[i][1] += __shfl_xor(g[i][1], m, 16);
      }
    }
    if (cq == 0) {
#pragma unroll
      for (int i = 0; i < 4; ++i) {
        gred[rg][i][0] = g[i][0];
        gred[rg][i][1] = g[i][1];
      }
    }
  }
  __syncthreads();

  // ---- project partial g through W2, atomic-accumulate ----
  if (tid < 64) {
    const int l = tid & 31, j = tid >> 5;
    float acc = 0.f;
#pragma unroll
    for (int rv = 0; rv < 64; ++rv)
      acc += W2[(128 + rv) * LL + l] * gred[rv >> 2][rv & 3][j];
    atomicAdd(&out[b * (LL * 2) + l * 2 + j], acc);
  }
}

extern "C" void kernel_launch(void* const* d_in, const int* in_sizes, int n_in,
                              void* d_out, int out_size, void* d_ws,
                              size_t ws_size, hipStream_t stream) {
  const float* user = (const float*)d_in[0];
  const float* item = (const float*)d_in[1];
  const float* att = (const float*)d_in[2];
  const float* adj = (const float*)d_in[3];
  const float* iw = (const float*)d_in[4];
  const float* W1 = (const float*)d_in[5];
  const float* W2 = (const float*)d_in[6];
  float* out = (float*)d_out;

  hipMemsetAsync(d_out, 0, sizeof(float) * (size_t)out_size, stream);
  fused_kernel<<<dim3(CT, BB), 256, 0, stream>>>(user, item, att, adj, iw, W1,
                                                 W2, out);
}